// Round 20
// baseline (135.649 us; speedup 1.0000x reference)
//
#include <hip/hip_runtime.h>
#include <stdint.h>

typedef _Float16 f16;
typedef __attribute__((ext_vector_type(8))) _Float16 f16x8;
typedef __attribute__((ext_vector_type(4))) float f32x4;
typedef __attribute__((ext_vector_type(2))) unsigned int u32x2;
typedef __attribute__((ext_vector_type(4))) unsigned int u32x4;
typedef decltype(__builtin_amdgcn_cvt_pkrtz(0.f, 0.f)) h2_t;

#define S_LEN 2048
#define BATCH 8
#define D_IN  1024
#define DHALF 512

__device__ __forceinline__ unsigned lds_off(const void* p) {
  return (unsigned)(size_t)p;
}

// async global->LDS DMA, 16B per lane (dest = wave-uniform base + lane*16 by HW)
__device__ __forceinline__ void dma16(const void* g, void* lds_uniform) {
  __builtin_amdgcn_global_load_lds(
      (const __attribute__((address_space(1))) void*)g,
      (__attribute__((address_space(3))) void*)lds_uniform, 16, 0, 0);
}

// ---------------------------------------------------------------------------
// W f32 -> f16 preconvert (one-shot, ~3MB): out[z] = (f16)W[z], layout [n][k].
// ---------------------------------------------------------------------------
__global__ __launch_bounds__(256) void wcvt_kernel(
    const float* __restrict__ Wq, const float* __restrict__ Wk, const float* __restrict__ Wv,
    f16* __restrict__ out)
{
  const int z = blockIdx.y;
  const float* W = (z == 0) ? Wq : (z == 1) ? Wk : Wv;
  const int idx = (blockIdx.x * 256 + threadIdx.x) * 8;
  f32x4 a = *(const f32x4*)(W + idx);
  f32x4 b = *(const f32x4*)(W + idx + 4);
  union { h2_t h2[4]; f16x8 v; } u;
  u.h2[0] = __builtin_amdgcn_cvt_pkrtz(a.x, a.y);
  u.h2[1] = __builtin_amdgcn_cvt_pkrtz(a.z, a.w);
  u.h2[2] = __builtin_amdgcn_cvt_pkrtz(b.x, b.y);
  u.h2[3] = __builtin_amdgcn_cvt_pkrtz(b.z, b.w);
  *(f16x8*)(out + (size_t)z * (DHALF * D_IN) + idx) = u.v;
}

// ---------------------------------------------------------------------------
// Projection v8 (r15 champion, untouched). BM=128 x BN=512, 8 waves.
// ---------------------------------------------------------------------------
__global__ __launch_bounds__(512, 1) void proj_kernel(
    const float* __restrict__ Xq, const float* __restrict__ Xk, const float* __restrict__ Xv,
    const f16* __restrict__ Wf16,
    const float* __restrict__ bq, const float* __restrict__ bk, const float* __restrict__ bv,
    f16* __restrict__ oq, f16* __restrict__ ok, f16* __restrict__ ov)
{
  const int z = blockIdx.z;
  const float* X    = (z == 0) ? Xq : (z == 1) ? Xk : Xv;
  const f16*   W    = Wf16 + (size_t)z * (DHALF * D_IN);
  const float* bias = (z == 0) ? bq : (z == 1) ? bk : bv;
  f16* out          = (z == 0) ? oq : (z == 1) ? ok : ov;

  const int m0 = blockIdx.x * 128;
  const int tid = threadIdx.x;
  const int lane = tid & 63;
  const int w = tid >> 6;               // wave 0..7 = n-column group (64 cols)
  const int rl = lane & 15, g = lane >> 4;

  __shared__ char Ab[2][16384];         // [128 rows][128B k] f16, XOR-swizzled
  __shared__ char Bb[65536];            // [512 rows][128B k] f16, wave-local 1/8ths

  f32x4 acc[8][4];
#pragma unroll
  for (int i = 0; i < 8; i++)
#pragma unroll
    for (int j = 0; j < 4; j++) acc[i][j] = (f32x4){0.f, 0.f, 0.f, 0.f};

  const int arow0 = w * 16 + (lane >> 4);
  const char* gA = (const char*)X + (size_t)(m0 + arow0) * (D_IN * 4) + (lane & 15) * 16;
  const unsigned awkb = (unsigned)(lane & 15) * 8;

  const int brow0 = w * 64 + (lane >> 3);
  const char* gBs = (const char*)W + (size_t)brow0 * (D_IN * 2)
                    + ((((unsigned)(lane & 7)) * 16) ^ (((unsigned)(lane >> 3)) << 4));
  const unsigned bdst0 = (unsigned)w * 8192;

  f32x4 aS[4];

#define LOAD_A(KC) {                                                          \
  _Pragma("unroll")                                                           \
  for (int i = 0; i < 4; i++)                                                 \
    aS[i] = __builtin_nontemporal_load(                                       \
        (const f32x4*)(gA + (size_t)i * 4 * (D_IN * 4) + (size_t)(KC) * 256)); }

#define WRITE_A(BUF) {                                                        \
  _Pragma("unroll")                                                           \
  for (int i = 0; i < 4; i++) {                                               \
    int row = arow0 + i * 4;                                                  \
    union { h2_t h[2]; u32x2 u; } d;                                          \
    d.h[0] = __builtin_amdgcn_cvt_pkrtz(aS[i].x, aS[i].y);                    \
    d.h[1] = __builtin_amdgcn_cvt_pkrtz(aS[i].z, aS[i].w);                    \
    *(u32x2*)(&Ab[BUF][0] + (unsigned)row * 128 +                             \
              (awkb ^ (((unsigned)(row & 7)) << 4))) = d.u;                   \
  } }

#define DMA_B(KC) {                                                           \
  _Pragma("unroll")                                                           \
  for (int i = 0; i < 8; i++)                                                 \
    dma16(gBs + (size_t)i * 8 * (D_IN * 2) + (size_t)(KC) * 128,              \
          &Bb[0] + bdst0 + (unsigned)i * 1024u); }

#define KSTEP_AF(BUF, KS, BF) {                                               \
  _Pragma("unroll")                                                           \
  for (int m = 0; m < 8; m++) {                                               \
    unsigned arow = (unsigned)(m * 16 + rl);                                  \
    f16x8 af = *(const f16x8*)(&Ab[BUF][0] + arow * 128 +                     \
             ((unsigned)((KS) * 64 + g * 16) ^ (((unsigned)(rl & 7)) << 4))); \
    _Pragma("unroll")                                                         \
    for (int nf = 0; nf < 4; nf++)                                            \
      acc[m][nf] = __builtin_amdgcn_mfma_f32_16x16x32_f16(                    \
          af, BF[nf], acc[m][nf], 0, 0, 0);                                   \
  } }

  // prologue
  LOAD_A(0);
  WRITE_A(0);
  DMA_B(0);
  LOAD_A(1);
  asm volatile("s_waitcnt lgkmcnt(0)" ::: "memory");
  __builtin_amdgcn_s_barrier();
  asm volatile("s_waitcnt vmcnt(4)" ::: "memory");
  __builtin_amdgcn_sched_barrier(0);

  int cur = 0;
  for (int kc = 0; kc < 16; ++kc) {
    f16x8 bf0[4], bf1[4];
#pragma unroll
    for (int nf = 0; nf < 4; nf++) {
      unsigned nrow = (unsigned)(w * 64 + nf * 16 + rl);
      unsigned swz  = ((unsigned)(rl & 7)) << 4;
      bf0[nf] = *(const f16x8*)(&Bb[0] + nrow * 128 + (((unsigned)(g * 16)) ^ swz));
      bf1[nf] = *(const f16x8*)(&Bb[0] + nrow * 128 + (((unsigned)(64 + g * 16)) ^ swz));
    }
    asm volatile("s_waitcnt lgkmcnt(0)" ::: "memory");
    __builtin_amdgcn_sched_barrier(0);

    if (kc < 15) { DMA_B(kc + 1); }

    KSTEP_AF(cur, 0, bf0);
    KSTEP_AF(cur, 1, bf1);

    if (kc < 15) {
      WRITE_A(cur ^ 1);
      asm volatile("s_waitcnt lgkmcnt(0)" ::: "memory");
      __builtin_amdgcn_s_barrier();
      if (kc < 14) {
        LOAD_A(kc + 2);
        asm volatile("s_waitcnt vmcnt(4)" ::: "memory");
      } else {
        asm volatile("s_waitcnt vmcnt(0)" ::: "memory");
      }
      __builtin_amdgcn_sched_barrier(0);
      cur ^= 1;
    }
  }
#undef LOAD_A
#undef WRITE_A
#undef DMA_B
#undef KSTEP_AF

#pragma unroll
  for (int m = 0; m < 8; m++) {
    const int row = m0 + m * 16 + g * 4;
#pragma unroll
    for (int nf = 0; nf < 4; nf++) {
      const int col = w * 64 + nf * 16 + rl;
      const float bb = bias[col];
#pragma unroll
      for (int r = 0; r < 4; r++)
        out[(size_t)(row + r) * DHALF + col] = (f16)(acc[m][nf][r] + bb);
    }
  }
}

// ---------------------------------------------------------------------------
// Batched GEMM-TN v5 = v4 (XCD-pinned, depth-3 QK / depth-2 PV) +
// NONTEMPORAL output stores for EPI==1 (PV): the 32MB once-written f32
// output no longer write-allocates in L2, preserving the XCD-pinned vt
// panels that r19 made resident.
// ---------------------------------------------------------------------------
template <int EPI, int MI>
__global__ __launch_bounds__(256, 3) void gemm_tn2_kernel(
    const f16* __restrict__ A, long batchA, int lda,
    const f16* __restrict__ Bm, long batchB, int ldb,
    int Ksize,
    const int* __restrict__ mask,
    float* __restrict__ out, long batchOut, int ldo)
{
  constexpr int BM   = MI * 32;
  constexpr int NA   = BM / 64;
  constexpr int ASZ  = BM * 64;
  constexpr int SSZ  = ASZ + 8192;
  constexpr int NBUF = (MI == 2) ? 4 : 3;

  // XCD-pinned decode: id%8 = batch -> one XCD per batch (round-robin heuristic)
  const int id = blockIdx.x;
  const int bz = id & 7;
  const int rr = id >> 3;
  const int bx = (MI == 2) ? (rr & 3) : (rr & 15);
  const int by = (MI == 2) ? (rr >> 2) : (rr >> 4);
  const int n0 = bx * 128;
  const int m0 = by * BM;
  const char* Abase = (const char*)(A + (size_t)bz * batchA);
  const char* Bbase = (const char*)(Bm + (size_t)bz * batchB);

  const int tid = threadIdx.x, lane = tid & 63, wave = tid >> 6;
  const int wr = wave >> 1, wc = wave & 1;
  const int g = lane >> 4, rl = lane & 15;

  __shared__ char Buf[NBUF][SSZ];

  f32x4 acc[MI][4];
#pragma unroll
  for (int i = 0; i < MI; i++)
#pragma unroll
    for (int j = 0; j < 4; j++) acc[i][j] = (f32x4){0.f, 0.f, 0.f, 0.f};

  const char* gAsrc[NA];
  unsigned    ldsA[NA];
#pragma unroll
  for (int i = 0; i < NA; i++) {
    int row = wave * (BM / 4) + i * 16 + (lane >> 2);
    unsigned kbyte = (((unsigned)(lane & 3)) * 16) ^ ((((unsigned)lane >> 3) & 3u) << 4);
    gAsrc[i] = Abase + (size_t)(m0 + row) * lda * 2 + kbyte;
    ldsA[i]  = (unsigned)(wave * (BM / 4) + i * 16) * 64;
  }
  const char* gBsrc[2];
  unsigned    ldsB[2];
#pragma unroll
  for (int i = 0; i < 2; i++) {
    int nb   = wave * 2 + i;
    int phys = lane >> 3;
    int kb   = (phys & 3) * 2 + (phys >> 2);
    int kk   = kb * 4 + ((lane >> 1) & 3);
    int nn   = nb * 16 + (lane & 1) * 8;
    gBsrc[i] = Bbase + (size_t)kk * ldb * 2 + (size_t)(n0 + nn) * 2;
    ldsB[i]  = (unsigned)(ASZ + nb * 1024);
  }

#define ISSUE(BUF, STEP) {                                                    \
  _Pragma("unroll")                                                           \
  for (int i = 0; i < NA; i++)                                                \
    dma16(gAsrc[i] + (size_t)(STEP) * 64, &Buf[BUF][0] + ldsA[i]);            \
  _Pragma("unroll")                                                           \
  for (int i = 0; i < 2; i++)                                                 \
    dma16(gBsrc[i] + (size_t)(STEP) * 32 * ldb * 2, &Buf[BUF][0] + ldsB[i]); }

#define COMPUTE(BUF) {                                                        \
  f16x8 af[MI];                                                               \
  _Pragma("unroll")                                                           \
  for (int i = 0; i < MI; i++) {                                              \
    unsigned row  = (unsigned)(wr * (MI * 16) + i * 16 + rl);                 \
    unsigned byte = ((unsigned)(g * 16)) ^ ((((unsigned)rl >> 1) & 3u) << 4); \
    af[i] = *(const f16x8*)(&Buf[BUF][0] + row * 64 + byte);                  \
  }                                                                           \
  f16x8 bf[4];                                                                \
  _Pragma("unroll")                                                           \
  for (int j = 0; j < 4; j++) {                                               \
    unsigned addr = lds_off(&Buf[BUF][0]) + (unsigned)ASZ +                   \
                    (unsigned)((wc * 4 + j) * 1024) + (unsigned)lane * 8u;    \
    u32x2 lo, hi;                                                             \
    asm volatile("ds_read_b64_tr_b16 %0, %1" : "=v"(lo) : "v"(addr));         \
    asm volatile("ds_read_b64_tr_b16 %0, %1 offset:512" : "=v"(hi) : "v"(addr)); \
    union { u32x4 u; f16x8 h; } cc;                                           \
    cc.u = (u32x4){lo.x, lo.y, hi.x, hi.y};                                   \
    bf[j] = cc.h;                                                             \
  }                                                                           \
  asm volatile("s_waitcnt lgkmcnt(0)" ::: "memory");                          \
  __builtin_amdgcn_sched_barrier(0);                                          \
  _Pragma("unroll")                                                           \
  for (int i = 0; i < MI; i++)                                                \
    _Pragma("unroll")                                                         \
    for (int j = 0; j < 4; j++)                                               \
      acc[i][j] = __builtin_amdgcn_mfma_f32_16x16x32_f16(af[i], bf[j], acc[i][j], 0, 0, 0); }

  const int NK = Ksize >> 5;
  ISSUE(0, 0);
  ISSUE(1, 1);
  if (NBUF == 4) { ISSUE(2, 2); }

  int cb = 0, ib = NBUF - 1;
  for (int k = 0; k < NK; ++k) {
    const int rem = NK - 1 - k;            // younger steps still needed
    if (NBUF == 4) {
      if (rem >= 2)      { asm volatile("s_waitcnt vmcnt(6)" ::: "memory"); }
      else if (rem == 1) { asm volatile("s_waitcnt vmcnt(3)" ::: "memory"); }
      else               { asm volatile("s_waitcnt vmcnt(0)" ::: "memory"); }
    } else {
      if (rem >= 1)      { asm volatile("s_waitcnt vmcnt(4)" ::: "memory"); }
      else               { asm volatile("s_waitcnt vmcnt(0)" ::: "memory"); }
    }
    __builtin_amdgcn_s_barrier();          // all waves' step-k dma landed
    __builtin_amdgcn_sched_barrier(0);
    if (k + NBUF - 1 < NK) {
      ISSUE(ib, k + NBUF - 1);             // buffer freed by compute(k-1)
      ib = (ib == NBUF - 1) ? 0 : ib + 1;
    }
    COMPUTE(cb);
    cb = (cb == NBUF - 1) ? 0 : cb + 1;
  }
#undef ISSUE
#undef COMPUTE

  float* ob = out + (size_t)bz * batchOut;
#pragma unroll
  for (int i = 0; i < MI; i++) {
    const int row = m0 + wr * (MI * 16) + i * 16 + g * 4;
#pragma unroll
    for (int j = 0; j < 4; j++) {
      const int col = n0 + wc * 64 + j * 16 + rl;
#pragma unroll
      for (int r = 0; r < 4; r++) {
        float val = acc[i][j][r];
        if (EPI == 0) {
          if (mask[(row + r) * DHALF + col] != 0) val = -1e30f;
          ob[(size_t)(row + r) * ldo + col] = val;
        } else {
          // once-written output: NT store, don't evict pinned vt panels
          __builtin_nontemporal_store(val, &ob[(size_t)(row + r) * ldo + col]);
        }
      }
    }
  }
}

// ---------------------------------------------------------------------------
// Row softmax over e (512), XCD-pinned: id%8 = batch so each batch's rows
// are processed on the XCD where QK wrote its logits and PV will read P.
// One wave per row; fp16 output.
// ---------------------------------------------------------------------------
__global__ __launch_bounds__(256) void softmax_kernel(
    const float* __restrict__ logits, f16* __restrict__ P)
{
  const int id = blockIdx.x;
  const int bz = id & 7;
  const int rg = id >> 3;                       // 0..127 row-group within batch
  const int row  = bz * 512 + rg * 4 + (threadIdx.x >> 6);
  const int lane = threadIdx.x & 63;
  const float* rp = logits + (size_t)row * DHALF + lane * 8;
  f32x4 x0 = *(const f32x4*)rp;
  f32x4 x1 = *(const f32x4*)(rp + 4);

  float m = fmaxf(fmaxf(fmaxf(x0.x, x0.y), fmaxf(x0.z, x0.w)),
                  fmaxf(fmaxf(x1.x, x1.y), fmaxf(x1.z, x1.w)));
#pragma unroll
  for (int off = 32; off > 0; off >>= 1) m = fmaxf(m, __shfl_xor(m, off, 64));

  float e0 = __expf(x0.x - m), e1 = __expf(x0.y - m);
  float e2 = __expf(x0.z - m), e3 = __expf(x0.w - m);
  float e4 = __expf(x1.x - m), e5 = __expf(x1.y - m);
  float e6 = __expf(x1.z - m), e7 = __expf(x1.w - m);
  float s = ((e0 + e1) + (e2 + e3)) + ((e4 + e5) + (e6 + e7));
#pragma unroll
  for (int off = 32; off > 0; off >>= 1) s += __shfl_xor(s, off, 64);
  const float inv = 1.0f / s;

  union { h2_t h2[4]; f16x8 v; } o;
  o.h2[0] = __builtin_amdgcn_cvt_pkrtz(e0 * inv, e1 * inv);
  o.h2[1] = __builtin_amdgcn_cvt_pkrtz(e2 * inv, e3 * inv);
  o.h2[2] = __builtin_amdgcn_cvt_pkrtz(e4 * inv, e5 * inv);
  o.h2[3] = __builtin_amdgcn_cvt_pkrtz(e6 * inv, e7 * inv);
  *(f16x8*)(P + (size_t)row * DHALF + lane * 8) = o.v;
}

// ---------------------------------------------------------------------------
extern "C" void kernel_launch(void* const* d_in, const int* in_sizes, int n_in,
                              void* d_out, int out_size, void* d_ws, size_t ws_size,
                              hipStream_t stream) {
  const float* q    = (const float*)d_in[0];
  const float* k    = (const float*)d_in[1];
  const float* v    = (const float*)d_in[2];
  const int*   mask = (const int*)d_in[3];
  const float* Wq   = (const float*)d_in[4];
  const float* bq   = (const float*)d_in[5];
  const float* Wk   = (const float*)d_in[6];
  const float* bk   = (const float*)d_in[7];
  const float* Wv   = (const float*)d_in[8];
  const float* bv   = (const float*)d_in[9];

  char* ws = (char*)d_ws;
  f16*   qt     = (f16*)(ws);                                  // 16 MB
  f16*   kt     = (f16*)(ws + 16777216);                       // 16 MB
  f16*   vt     = (f16*)(ws + 2 * 16777216);                   // 16 MB
  float* logits = (float*)(ws + 3 * 16777216);                 // 8 MB
  f16*   P      = (f16*)(ws + 3 * 16777216 + 8388608);         // 4 MB
  // Wf16 (3 MB) overlaps the logits region (consumed before QK writes logits)
  f16*   Wf16   = (f16*)(ws + 3 * 16777216);

  // 0) preconvert weights to fp16
  wcvt_kernel<<<dim3(256, 3), 256, 0, stream>>>(Wq, Wk, Wv, Wf16);
  // 1) fused q/k/v projections -> fp16 (S,B,DH) flat; BM=128, B-issue-early
  proj_kernel<<<dim3(128, 1, 3), 512, 0, stream>>>(q, k, v, Wf16, bq, bk, bv,
                                                   qt, kt, vt);
  // 2) logits[b,d,e] = sum_s q_[b,d,s] k_[b,s,e] (+mask); 256 blocks,
  //    XCD-pinned (id%8 = batch), depth-3 pipe
  gemm_tn2_kernel<0, 2><<<dim3(256), 256, 0, stream>>>(
      qt, 1048576L, 2048, kt, 1048576L, 512, 2048, mask, logits, 262144L, 512);
  // 3) P = softmax(logits) over e, fp16; XCD-pinned to batch
  softmax_kernel<<<dim3(1024), 256, 0, stream>>>(logits, P);
  // 4) out[b,d,s] = sum_e P[b,d,e] v_[b,e,s] -> f32 d_out; 512 blocks,
  //    XCD-pinned, depth-2, NT output stores
  gemm_tn2_kernel<1, 4><<<dim3(512), 256, 0, stream>>>(
      P, 262144L, 512, vt, 1048576L, 2048, 512, nullptr, (float*)d_out, 1048576L, 2048);
}

// Round 21
// 132.345 us; speedup vs baseline: 1.0250x; 1.0250x over previous
//
#include <hip/hip_runtime.h>
#include <stdint.h>

typedef _Float16 f16;
typedef __attribute__((ext_vector_type(8))) _Float16 f16x8;
typedef __attribute__((ext_vector_type(4))) float f32x4;
typedef __attribute__((ext_vector_type(2))) unsigned int u32x2;
typedef __attribute__((ext_vector_type(4))) unsigned int u32x4;
typedef decltype(__builtin_amdgcn_cvt_pkrtz(0.f, 0.f)) h2_t;

#define S_LEN 2048
#define BATCH 8
#define D_IN  1024
#define DHALF 512

__device__ __forceinline__ unsigned lds_off(const void* p) {
  return (unsigned)(size_t)p;
}

// async global->LDS DMA, 16B per lane (dest = wave-uniform base + lane*16 by HW)
__device__ __forceinline__ void dma16(const void* g, void* lds_uniform) {
  __builtin_amdgcn_global_load_lds(
      (const __attribute__((address_space(1))) void*)g,
      (__attribute__((address_space(3))) void*)lds_uniform, 16, 0, 0);
}

// ---------------------------------------------------------------------------
// W f32 -> f16 preconvert (one-shot, ~3MB): out[z] = (f16)W[z], layout [n][k].
// ---------------------------------------------------------------------------
__global__ __launch_bounds__(256) void wcvt_kernel(
    const float* __restrict__ Wq, const float* __restrict__ Wk, const float* __restrict__ Wv,
    f16* __restrict__ out)
{
  const int z = blockIdx.y;
  const float* W = (z == 0) ? Wq : (z == 1) ? Wk : Wv;
  const int idx = (blockIdx.x * 256 + threadIdx.x) * 8;
  f32x4 a = *(const f32x4*)(W + idx);
  f32x4 b = *(const f32x4*)(W + idx + 4);
  union { h2_t h2[4]; f16x8 v; } u;
  u.h2[0] = __builtin_amdgcn_cvt_pkrtz(a.x, a.y);
  u.h2[1] = __builtin_amdgcn_cvt_pkrtz(a.z, a.w);
  u.h2[2] = __builtin_amdgcn_cvt_pkrtz(b.x, b.y);
  u.h2[3] = __builtin_amdgcn_cvt_pkrtz(b.z, b.w);
  *(f16x8*)(out + (size_t)z * (DHALF * D_IN) + idx) = u.v;
}

// ---------------------------------------------------------------------------
// Projection v8 (r15 champion). BM=128 x BN=512, 8 waves.
// Per kc: bf reads (both ks) -> lgkmcnt(0) -> DMA_B(kc+1) issued EARLY
//         -> KSTEP0/1 MFMA -> WRITE_A -> barrier -> LOAD_A(kc+2) -> vmcnt(4)
// A: once-chip-wide 256B NT runs -> reg -> cvt f16 -> XOR-swizzled LDS
// [128][128B], dbuf, ONE raw barrier per kc64. LDS 96KB. Grid (128,1,3).
// ---------------------------------------------------------------------------
__global__ __launch_bounds__(512, 1) void proj_kernel(
    const float* __restrict__ Xq, const float* __restrict__ Xk, const float* __restrict__ Xv,
    const f16* __restrict__ Wf16,
    const float* __restrict__ bq, const float* __restrict__ bk, const float* __restrict__ bv,
    f16* __restrict__ oq, f16* __restrict__ ok, f16* __restrict__ ov)
{
  const int z = blockIdx.z;
  const float* X    = (z == 0) ? Xq : (z == 1) ? Xk : Xv;
  const f16*   W    = Wf16 + (size_t)z * (DHALF * D_IN);
  const float* bias = (z == 0) ? bq : (z == 1) ? bk : bv;
  f16* out          = (z == 0) ? oq : (z == 1) ? ok : ov;

  const int m0 = blockIdx.x * 128;
  const int tid = threadIdx.x;
  const int lane = tid & 63;
  const int w = tid >> 6;               // wave 0..7 = n-column group (64 cols)
  const int rl = lane & 15, g = lane >> 4;

  __shared__ char Ab[2][16384];         // [128 rows][128B k] f16, XOR-swizzled
  __shared__ char Bb[65536];            // [512 rows][128B k] f16, wave-local 1/8ths

  f32x4 acc[8][4];
#pragma unroll
  for (int i = 0; i < 8; i++)
#pragma unroll
    for (int j = 0; j < 4; j++) acc[i][j] = (f32x4){0.f, 0.f, 0.f, 0.f};

  const int arow0 = w * 16 + (lane >> 4);
  const char* gA = (const char*)X + (size_t)(m0 + arow0) * (D_IN * 4) + (lane & 15) * 16;
  const unsigned awkb = (unsigned)(lane & 15) * 8;

  const int brow0 = w * 64 + (lane >> 3);
  const char* gBs = (const char*)W + (size_t)brow0 * (D_IN * 2)
                    + ((((unsigned)(lane & 7)) * 16) ^ (((unsigned)(lane >> 3)) << 4));
  const unsigned bdst0 = (unsigned)w * 8192;

  f32x4 aS[4];

#define LOAD_A(KC) {                                                          \
  _Pragma("unroll")                                                           \
  for (int i = 0; i < 4; i++)                                                 \
    aS[i] = __builtin_nontemporal_load(                                       \
        (const f32x4*)(gA + (size_t)i * 4 * (D_IN * 4) + (size_t)(KC) * 256)); }

#define WRITE_A(BUF) {                                                        \
  _Pragma("unroll")                                                           \
  for (int i = 0; i < 4; i++) {                                               \
    int row = arow0 + i * 4;                                                  \
    union { h2_t h[2]; u32x2 u; } d;                                          \
    d.h[0] = __builtin_amdgcn_cvt_pkrtz(aS[i].x, aS[i].y);                    \
    d.h[1] = __builtin_amdgcn_cvt_pkrtz(aS[i].z, aS[i].w);                    \
    *(u32x2*)(&Ab[BUF][0] + (unsigned)row * 128 +                             \
              (awkb ^ (((unsigned)(row & 7)) << 4))) = d.u;                   \
  } }

#define DMA_B(KC) {                                                           \
  _Pragma("unroll")                                                           \
  for (int i = 0; i < 8; i++)                                                 \
    dma16(gBs + (size_t)i * 8 * (D_IN * 2) + (size_t)(KC) * 128,              \
          &Bb[0] + bdst0 + (unsigned)i * 1024u); }

#define KSTEP_AF(BUF, KS, BF) {                                               \
  _Pragma("unroll")                                                           \
  for (int m = 0; m < 8; m++) {                                               \
    unsigned arow = (unsigned)(m * 16 + rl);                                  \
    f16x8 af = *(const f16x8*)(&Ab[BUF][0] + arow * 128 +                     \
             ((unsigned)((KS) * 64 + g * 16) ^ (((unsigned)(rl & 7)) << 4))); \
    _Pragma("unroll")                                                         \
    for (int nf = 0; nf < 4; nf++)                                            \
      acc[m][nf] = __builtin_amdgcn_mfma_f32_16x16x32_f16(                    \
          af, BF[nf], acc[m][nf], 0, 0, 0);                                   \
  } }

  // prologue
  LOAD_A(0);
  WRITE_A(0);
  DMA_B(0);
  LOAD_A(1);
  asm volatile("s_waitcnt lgkmcnt(0)" ::: "memory");
  __builtin_amdgcn_s_barrier();
  asm volatile("s_waitcnt vmcnt(4)" ::: "memory");
  __builtin_amdgcn_sched_barrier(0);

  int cur = 0;
  for (int kc = 0; kc < 16; ++kc) {
    f16x8 bf0[4], bf1[4];
#pragma unroll
    for (int nf = 0; nf < 4; nf++) {
      unsigned nrow = (unsigned)(w * 64 + nf * 16 + rl);
      unsigned swz  = ((unsigned)(rl & 7)) << 4;
      bf0[nf] = *(const f16x8*)(&Bb[0] + nrow * 128 + (((unsigned)(g * 16)) ^ swz));
      bf1[nf] = *(const f16x8*)(&Bb[0] + nrow * 128 + (((unsigned)(64 + g * 16)) ^ swz));
    }
    asm volatile("s_waitcnt lgkmcnt(0)" ::: "memory");
    __builtin_amdgcn_sched_barrier(0);

    if (kc < 15) { DMA_B(kc + 1); }

    KSTEP_AF(cur, 0, bf0);
    KSTEP_AF(cur, 1, bf1);

    if (kc < 15) {
      WRITE_A(cur ^ 1);
      asm volatile("s_waitcnt lgkmcnt(0)" ::: "memory");
      __builtin_amdgcn_s_barrier();
      if (kc < 14) {
        LOAD_A(kc + 2);
        asm volatile("s_waitcnt vmcnt(4)" ::: "memory");
      } else {
        asm volatile("s_waitcnt vmcnt(0)" ::: "memory");
      }
      __builtin_amdgcn_sched_barrier(0);
      cur ^= 1;
    }
  }
#undef LOAD_A
#undef WRITE_A
#undef DMA_B
#undef KSTEP_AF

#pragma unroll
  for (int m = 0; m < 8; m++) {
    const int row = m0 + m * 16 + g * 4;
#pragma unroll
    for (int nf = 0; nf < 4; nf++) {
      const int col = w * 64 + nf * 16 + rl;
      const float bb = bias[col];
#pragma unroll
      for (int r = 0; r < 4; r++)
        out[(size_t)(row + r) * DHALF + col] = (f16)(acc[m][nf][r] + bb);
    }
  }
}

// ---------------------------------------------------------------------------
// Batched GEMM-TN v4 = v3 pipeline + XCD-pinned batch mapping (T1).
// 1-D grid, in-kernel decode with linear_id % 8 == batch, so (assuming
// round-robin workgroup->XCD dispatch) each batch's blocks land on ONE XCD
// and its kt/vt B-panel (2MB) stays resident in that XCD's 4MB L2 instead
// of being replicated/thrashed across all 8. Pure index permutation --
// correctness-identical to v3.
// NBUF = 4 (depth-3) for MI==2 (QK), 3 (depth-2) for MI==4 (PV); 3 blocks/CU.
// ---------------------------------------------------------------------------
template <int EPI, int MI>
__global__ __launch_bounds__(256, 3) void gemm_tn2_kernel(
    const f16* __restrict__ A, long batchA, int lda,
    const f16* __restrict__ Bm, long batchB, int ldb,
    int Ksize,
    const int* __restrict__ mask,
    float* __restrict__ out, long batchOut, int ldo)
{
  constexpr int BM   = MI * 32;
  constexpr int NA   = BM / 64;
  constexpr int ASZ  = BM * 64;
  constexpr int SSZ  = ASZ + 8192;
  constexpr int NBUF = (MI == 2) ? 4 : 3;

  // XCD-pinned decode: id%8 = batch -> one XCD per batch (round-robin heuristic)
  const int id = blockIdx.x;
  const int bz = id & 7;
  const int rr = id >> 3;
  const int bx = (MI == 2) ? (rr & 3) : (rr & 15);
  const int by = (MI == 2) ? (rr >> 2) : (rr >> 4);
  const int n0 = bx * 128;
  const int m0 = by * BM;
  const char* Abase = (const char*)(A + (size_t)bz * batchA);
  const char* Bbase = (const char*)(Bm + (size_t)bz * batchB);

  const int tid = threadIdx.x, lane = tid & 63, wave = tid >> 6;
  const int wr = wave >> 1, wc = wave & 1;
  const int g = lane >> 4, rl = lane & 15;

  __shared__ char Buf[NBUF][SSZ];

  f32x4 acc[MI][4];
#pragma unroll
  for (int i = 0; i < MI; i++)
#pragma unroll
    for (int j = 0; j < 4; j++) acc[i][j] = (f32x4){0.f, 0.f, 0.f, 0.f};

  const char* gAsrc[NA];
  unsigned    ldsA[NA];
#pragma unroll
  for (int i = 0; i < NA; i++) {
    int row = wave * (BM / 4) + i * 16 + (lane >> 2);
    unsigned kbyte = (((unsigned)(lane & 3)) * 16) ^ ((((unsigned)lane >> 3) & 3u) << 4);
    gAsrc[i] = Abase + (size_t)(m0 + row) * lda * 2 + kbyte;
    ldsA[i]  = (unsigned)(wave * (BM / 4) + i * 16) * 64;
  }
  const char* gBsrc[2];
  unsigned    ldsB[2];
#pragma unroll
  for (int i = 0; i < 2; i++) {
    int nb   = wave * 2 + i;
    int phys = lane >> 3;
    int kb   = (phys & 3) * 2 + (phys >> 2);
    int kk   = kb * 4 + ((lane >> 1) & 3);
    int nn   = nb * 16 + (lane & 1) * 8;
    gBsrc[i] = Bbase + (size_t)kk * ldb * 2 + (size_t)(n0 + nn) * 2;
    ldsB[i]  = (unsigned)(ASZ + nb * 1024);
  }

#define ISSUE(BUF, STEP) {                                                    \
  _Pragma("unroll")                                                           \
  for (int i = 0; i < NA; i++)                                                \
    dma16(gAsrc[i] + (size_t)(STEP) * 64, &Buf[BUF][0] + ldsA[i]);            \
  _Pragma("unroll")                                                           \
  for (int i = 0; i < 2; i++)                                                 \
    dma16(gBsrc[i] + (size_t)(STEP) * 32 * ldb * 2, &Buf[BUF][0] + ldsB[i]); }

#define COMPUTE(BUF) {                                                        \
  f16x8 af[MI];                                                               \
  _Pragma("unroll")                                                           \
  for (int i = 0; i < MI; i++) {                                              \
    unsigned row  = (unsigned)(wr * (MI * 16) + i * 16 + rl);                 \
    unsigned byte = ((unsigned)(g * 16)) ^ ((((unsigned)rl >> 1) & 3u) << 4); \
    af[i] = *(const f16x8*)(&Buf[BUF][0] + row * 64 + byte);                  \
  }                                                                           \
  f16x8 bf[4];                                                                \
  _Pragma("unroll")                                                           \
  for (int j = 0; j < 4; j++) {                                               \
    unsigned addr = lds_off(&Buf[BUF][0]) + (unsigned)ASZ +                   \
                    (unsigned)((wc * 4 + j) * 1024) + (unsigned)lane * 8u;    \
    u32x2 lo, hi;                                                             \
    asm volatile("ds_read_b64_tr_b16 %0, %1" : "=v"(lo) : "v"(addr));         \
    asm volatile("ds_read_b64_tr_b16 %0, %1 offset:512" : "=v"(hi) : "v"(addr)); \
    union { u32x4 u; f16x8 h; } cc;                                           \
    cc.u = (u32x4){lo.x, lo.y, hi.x, hi.y};                                   \
    bf[j] = cc.h;                                                             \
  }                                                                           \
  asm volatile("s_waitcnt lgkmcnt(0)" ::: "memory");                          \
  __builtin_amdgcn_sched_barrier(0);                                          \
  _Pragma("unroll")                                                           \
  for (int i = 0; i < MI; i++)                                                \
    _Pragma("unroll")                                                         \
    for (int j = 0; j < 4; j++)                                               \
      acc[i][j] = __builtin_amdgcn_mfma_f32_16x16x32_f16(af[i], bf[j], acc[i][j], 0, 0, 0); }

  const int NK = Ksize >> 5;
  ISSUE(0, 0);
  ISSUE(1, 1);
  if (NBUF == 4) { ISSUE(2, 2); }

  int cb = 0, ib = NBUF - 1;
  for (int k = 0; k < NK; ++k) {
    const int rem = NK - 1 - k;            // younger steps still needed
    if (NBUF == 4) {
      if (rem >= 2)      { asm volatile("s_waitcnt vmcnt(6)" ::: "memory"); }
      else if (rem == 1) { asm volatile("s_waitcnt vmcnt(3)" ::: "memory"); }
      else               { asm volatile("s_waitcnt vmcnt(0)" ::: "memory"); }
    } else {
      if (rem >= 1)      { asm volatile("s_waitcnt vmcnt(4)" ::: "memory"); }
      else               { asm volatile("s_waitcnt vmcnt(0)" ::: "memory"); }
    }
    __builtin_amdgcn_s_barrier();          // all waves' step-k dma landed
    __builtin_amdgcn_sched_barrier(0);
    if (k + NBUF - 1 < NK) {
      ISSUE(ib, k + NBUF - 1);             // buffer freed by compute(k-1)
      ib = (ib == NBUF - 1) ? 0 : ib + 1;
    }
    COMPUTE(cb);
    cb = (cb == NBUF - 1) ? 0 : cb + 1;
  }
#undef ISSUE
#undef COMPUTE

  float* ob = out + (size_t)bz * batchOut;
#pragma unroll
  for (int i = 0; i < MI; i++) {
    const int row = m0 + wr * (MI * 16) + i * 16 + g * 4;
#pragma unroll
    for (int j = 0; j < 4; j++) {
      const int col = n0 + wc * 64 + j * 16 + rl;
#pragma unroll
      for (int r = 0; r < 4; r++) {
        float val = acc[i][j][r];
        if (EPI == 0) {
          if (mask[(row + r) * DHALF + col] != 0) val = -1e30f;
        }
        ob[(size_t)(row + r) * ldo + col] = val;
      }
    }
  }
}

// ---------------------------------------------------------------------------
// Row softmax over e (512) for 4096 rows; one wave per row; fp16 output.
// ---------------------------------------------------------------------------
__global__ __launch_bounds__(256) void softmax_kernel(
    const float* __restrict__ logits, f16* __restrict__ P)
{
  const int row  = blockIdx.x * 4 + (threadIdx.x >> 6);
  const int lane = threadIdx.x & 63;
  const float* rp = logits + (size_t)row * DHALF + lane * 8;
  f32x4 x0 = *(const f32x4*)rp;
  f32x4 x1 = *(const f32x4*)(rp + 4);

  float m = fmaxf(fmaxf(fmaxf(x0.x, x0.y), fmaxf(x0.z, x0.w)),
                  fmaxf(fmaxf(x1.x, x1.y), fmaxf(x1.z, x1.w)));
#pragma unroll
  for (int off = 32; off > 0; off >>= 1) m = fmaxf(m, __shfl_xor(m, off, 64));

  float e0 = __expf(x0.x - m), e1 = __expf(x0.y - m);
  float e2 = __expf(x0.z - m), e3 = __expf(x0.w - m);
  float e4 = __expf(x1.x - m), e5 = __expf(x1.y - m);
  float e6 = __expf(x1.z - m), e7 = __expf(x1.w - m);
  float s = ((e0 + e1) + (e2 + e3)) + ((e4 + e5) + (e6 + e7));
#pragma unroll
  for (int off = 32; off > 0; off >>= 1) s += __shfl_xor(s, off, 64);
  const float inv = 1.0f / s;

  union { h2_t h2[4]; f16x8 v; } o;
  o.h2[0] = __builtin_amdgcn_cvt_pkrtz(e0 * inv, e1 * inv);
  o.h2[1] = __builtin_amdgcn_cvt_pkrtz(e2 * inv, e3 * inv);
  o.h2[2] = __builtin_amdgcn_cvt_pkrtz(e4 * inv, e5 * inv);
  o.h2[3] = __builtin_amdgcn_cvt_pkrtz(e6 * inv, e7 * inv);
  *(f16x8*)(P + (size_t)row * DHALF + lane * 8) = o.v;
}

// ---------------------------------------------------------------------------
extern "C" void kernel_launch(void* const* d_in, const int* in_sizes, int n_in,
                              void* d_out, int out_size, void* d_ws, size_t ws_size,
                              hipStream_t stream) {
  const float* q    = (const float*)d_in[0];
  const float* k    = (const float*)d_in[1];
  const float* v    = (const float*)d_in[2];
  const int*   mask = (const int*)d_in[3];
  const float* Wq   = (const float*)d_in[4];
  const float* bq   = (const float*)d_in[5];
  const float* Wk   = (const float*)d_in[6];
  const float* bk   = (const float*)d_in[7];
  const float* Wv   = (const float*)d_in[8];
  const float* bv   = (const float*)d_in[9];

  char* ws = (char*)d_ws;
  f16*   qt     = (f16*)(ws);                                  // 16 MB
  f16*   kt     = (f16*)(ws + 16777216);                       // 16 MB
  f16*   vt     = (f16*)(ws + 2 * 16777216);                   // 16 MB
  float* logits = (float*)(ws + 3 * 16777216);                 // 8 MB
  f16*   P      = (f16*)(ws + 3 * 16777216 + 8388608);         // 4 MB
  // Wf16 (3 MB) overlaps the logits region (consumed before QK writes logits)
  f16*   Wf16   = (f16*)(ws + 3 * 16777216);

  // 0) preconvert weights to fp16
  wcvt_kernel<<<dim3(256, 3), 256, 0, stream>>>(Wq, Wk, Wv, Wf16);
  // 1) fused q/k/v projections -> fp16 (S,B,DH) flat; BM=128, B-issue-early
  proj_kernel<<<dim3(128, 1, 3), 512, 0, stream>>>(q, k, v, Wf16, bq, bk, bv,
                                                   qt, kt, vt);
  // 2) logits[b,d,e] = sum_s q_[b,d,s] k_[b,s,e] (+mask); 256 blocks,
  //    XCD-pinned (id%8 = batch), depth-3 pipe
  gemm_tn2_kernel<0, 2><<<dim3(256), 256, 0, stream>>>(
      qt, 1048576L, 2048, kt, 1048576L, 512, 2048, mask, logits, 262144L, 512);
  // 3) P = softmax(logits) over e, fp16
  softmax_kernel<<<dim3(1024), 256, 0, stream>>>(logits, P);
  // 4) out[b,d,s] = sum_e P[b,d,e] v_[b,e,s] -> f32 d_out; 512 blocks,
  //    XCD-pinned, depth-2
  gemm_tn2_kernel<1, 4><<<dim3(512), 256, 0, stream>>>(
      P, 262144L, 512, vt, 1048576L, 2048, 512, nullptr, (float*)d_out, 1048576L, 2048);
}